// Round 4
// baseline (243.705 us; speedup 1.0000x reference)
//
#include <hip/hip_runtime.h>

#define T_MAX 512
#define BATCH 32
#define CLASSES 1296
#define L_MAX 64
#define NROWS (T_MAX * BATCH)   // 16384
#define NV4 (CLASSES / 4)       // 324
#define NINF (-INFINITY)

// DPP wave64 sum: row_shr 1/2/4/8 + row_bcast 15/31. Total lands in LANE 63.
__device__ __forceinline__ float wave_sum64(float v) {
    v += __int_as_float(__builtin_amdgcn_update_dpp(0, __float_as_int(v), 0x111, 0xF, 0xF, true));
    v += __int_as_float(__builtin_amdgcn_update_dpp(0, __float_as_int(v), 0x112, 0xF, 0xF, true));
    v += __int_as_float(__builtin_amdgcn_update_dpp(0, __float_as_int(v), 0x114, 0xF, 0xF, true));
    v += __int_as_float(__builtin_amdgcn_update_dpp(0, __float_as_int(v), 0x118, 0xF, 0xF, true));
    v += __int_as_float(__builtin_amdgcn_update_dpp(0, __float_as_int(v), 0x142, 0xF, 0xF, true));
    v += __int_as_float(__builtin_amdgcn_update_dpp(0, __float_as_int(v), 0x143, 0xF, 0xF, true));
    return v;
}

// ---------------------------------------------------------------------------
// K1: single-pass row stats, one wave per row. ALL row loads issued before
// any consumption (keeps 6 float4 in flight -> one HBM round-trip per wave).
// DPP reduction (no LDS-pipe ops). Lane 63 stores. Seq waves also gather pb.
// ---------------------------------------------------------------------------
__global__ __launch_bounds__(256) void rowstats_kernel(
    const float* __restrict__ pred, const float* __restrict__ seqp,
    const int* __restrict__ label,
    float* __restrict__ lse_pred, float* __restrict__ sum_pred,
    float* __restrict__ lse_seq, float* __restrict__ pb, int* __restrict__ counter)
{
    int wid = blockIdx.x * 4 + (threadIdx.x >> 6);
    int lane = threadIdx.x & 63;
    if (wid == 0 && lane == 0) *counter = 0;      // for ce's last-block reduce
    bool isSeq = wid >= NROWS;
    int r = isSeq ? wid - NROWS : wid;            // r = t*BATCH + b
    const float* x = (isSeq ? seqp : pred) + (size_t)r * CLASSES;
    const float4* x4 = (const float4*)x;

    // ---- load phase: everything in flight before first use ----
    float4 q0 = x4[lane];
    float4 q1 = x4[lane + 64];
    float4 q2 = x4[lane + 128];
    float4 q3 = x4[lane + 192];
    float4 q4 = x4[lane + 256];
    float4 qt = make_float4(0.f, 0.f, 0.f, 0.f);
    if (lane < 4) qt = x4[320 + lane];            // tail: 324 float4 total
    int lab = 0;
    if (isSeq) lab = label[((r & 31) << 6) + lane];

    // ---- compute ----
    float s  = __expf(q0.x) + __expf(q0.y) + __expf(q0.z) + __expf(q0.w)
             + __expf(q1.x) + __expf(q1.y) + __expf(q1.z) + __expf(q1.w)
             + __expf(q2.x) + __expf(q2.y) + __expf(q2.z) + __expf(q2.w)
             + __expf(q3.x) + __expf(q3.y) + __expf(q3.z) + __expf(q3.w)
             + __expf(q4.x) + __expf(q4.y) + __expf(q4.z) + __expf(q4.w);
    float sx = (q0.x + q0.y + q0.z + q0.w) + (q1.x + q1.y + q1.z + q1.w)
             + (q2.x + q2.y + q2.z + q2.w) + (q3.x + q3.y + q3.z + q3.w)
             + (q4.x + q4.y + q4.z + q4.w);
    if (lane < 4) {
        s  += __expf(qt.x) + __expf(qt.y) + __expf(qt.z) + __expf(qt.w);
        sx += qt.x + qt.y + qt.z + qt.w;
    }
    s  = wave_sum64(s);
    sx = wave_sum64(sx);

    if (isSeq) {
        int b = r & 31, t = r >> 5;
        pb[(((size_t)(b << 9) + t) << 6) + lane] = x[lab];   // row is cache-warm
        if (lane == 63) lse_seq[r] = __logf(s);
    } else if (lane == 63) {
        lse_pred[r] = __logf(s);
        sum_pred[r] = sx;
    }
}

// ---------------------------------------------------------------------------
// K2: monotonic max-prob alignment (unchanged from R2 -- validated absmax 0.0).
// 2 waves/block: wave1 streams 64-col panels into LDS dbuf; wave0 runs the DP
// with DPP row_shr:1 + row_bcast15 for the lane shift. Outputs row index.
// ---------------------------------------------------------------------------
__global__ __launch_bounds__(128) void align_kernel(
    const float* __restrict__ pb, const int* __restrict__ x_len,
    const int* __restrict__ label_len, int* __restrict__ tg)
{
    int b = blockIdx.x;
    int tid = threadIdx.x, w = tid >> 6, lane = tid & 63;
    int C = x_len[b], R = label_len[b];
    int limit = C - R;
    __shared__ float buf[2][4096];              // two 64-col panels, 32 KB
    __shared__ unsigned long long ch[T_MAX];    // choice masks
    __shared__ int rows_s[T_MAX];
    const float* pbb = pb + ((size_t)b << 15);  // b * 512 * 64
    int P = (C + 63) >> 6;

    if (w == 1) {                               // prologue: panel 0
        const float4* s4 = (const float4*)pbb;
        float4* d4 = (float4*)buf[0];
        #pragma unroll
        for (int k = 0; k < 16; ++k) d4[(k << 6) + lane] = s4[(k << 6) + lane];
    }
    __syncthreads();

    float dp = NINF;
    const int ninf_i = 0xFF800000;              // bits of -inf

    for (int p = 0; p < P; ++p) {
        if (w == 1) {
            int ldp = p + 1; if (ldp > 7) ldp = 7;      // clamped prefetch
            const float4* s4 = (const float4*)(pbb + (ldp << 12));
            float4* d4 = (float4*)buf[(p + 1) & 1];
            #pragma unroll
            for (int k = 0; k < 16; ++k) d4[(k << 6) + lane] = s4[(k << 6) + lane];
        } else {
            const float* bc = buf[p & 1];
            int base = p << 6;
            unsigned long long m_local = 0ULL;
            #pragma unroll
            for (int g = 0; g < 4; ++g) {
                float v[16];
                #pragma unroll
                for (int u = 0; u < 16; ++u) v[u] = bc[((g << 4) + u) * 64 + lane];
                #pragma unroll
                for (int u = 0; u < 16; ++u) {
                    int kk = (g << 4) + u;
                    int j = base + kk;
                    if (kk == 0 && g == 0 && p == 0) {
                        dp = (lane == 0) ? v[0] : NINF;  // column 0 init
                    } else {
                        bool inband = (lane <= j) && (lane >= j - limit) && (lane < R);
                        float val = inband ? v[u] : NINF;
                        int dpb = __float_as_int(dp);
                        int t1 = __builtin_amdgcn_update_dpp(ninf_i, dpb, 0x111, 0xF, 0xF, false); // row_shr:1
                        int t2 = __builtin_amdgcn_update_dpp(ninf_i, dpb, 0x142, 0xF, 0xF, false); // row_bcast15
                        float shifted = __int_as_float(((lane & 15) == 0) ? t2 : t1);
                        bool c = shifted > dp;           // strict, as in reference
                        unsigned long long msk = __ballot(c);
                        dp = (c ? shifted : dp) + val;
                        m_local = (lane == kk) ? msk : m_local;
                    }
                }
            }
            ch[base + lane] = m_local;
        }
        __syncthreads();
    }

    if (tid == 0) {                             // backtrack, batched LDS reads
        int row = R - 1;
        int j2 = C - 1;
        while (j2 >= 0) {
            int bs = j2 & ~7;
            unsigned long long m[8];
            #pragma unroll
            for (int k = 0; k < 8; ++k) m[k] = ch[bs + k];
            for (int k = j2 - bs; k >= 0; --k) {
                rows_s[bs + k] = row;
                row -= (int)((m[k] >> row) & 1ULL);
            }
            j2 = bs - 1;
        }
    }
    __syncthreads();
    for (int j = tid; j < T_MAX; j += 128)
        tg[(b << 9) + j] = (j < C) ? rows_s[j] : -1;
}

// ---------------------------------------------------------------------------
// K3: per-element CE + fused last-block final reduction (agent-scope atomics).
// ---------------------------------------------------------------------------
__global__ __launch_bounds__(256) void ce_kernel(
    const float* __restrict__ pred, const int* __restrict__ label,
    const int* __restrict__ x_len,
    const float* __restrict__ lse_pred, const float* __restrict__ sum_pred,
    const float* __restrict__ lse_seq, const float* __restrict__ pb,
    const int* __restrict__ tg, float* __restrict__ partials,
    int* __restrict__ counter, float* __restrict__ out)
{
    int e = blockIdx.x * 256 + threadIdx.x;    // e = t*BATCH + b
    int t = e >> 5, b = e & 31;
    float ce = 0.f;
    if (t < x_len[b]) {
        int row = tg[(b << 9) + t];
        int tgt = label[(b << 6) + row];
        float lp = lse_pred[e];
        float S = sum_pred[e] - (float)CLASSES * lp;        // sum_v log_softmax(pred)
        float lsp_t = pred[(size_t)e * CLASSES + tgt] - lp;
        float conf = __expf(pb[(((size_t)(b << 9) + t) << 6) + row] - lse_seq[e]);
        float smooth = (1.f - conf) * (1.f / (float)(CLASSES - 1));
        ce = -((conf - smooth) * lsp_t + smooth * S);
    }
    ce = wave_sum64(ce);                        // total in lane 63
    __shared__ float sm[4];
    __shared__ int amLast;
    if ((threadIdx.x & 63) == 63) sm[threadIdx.x >> 6] = ce;
    __syncthreads();
    if (threadIdx.x == 0) {
        float p = sm[0] + sm[1] + sm[2] + sm[3];
        __hip_atomic_store(&partials[blockIdx.x], p, __ATOMIC_RELEASE, __HIP_MEMORY_SCOPE_AGENT);
        amLast = (__hip_atomic_fetch_add(counter, 1, __ATOMIC_ACQ_REL, __HIP_MEMORY_SCOPE_AGENT) == 63);
    }
    __syncthreads();
    if (amLast && threadIdx.x < 64) {
        float v = __hip_atomic_load(&partials[threadIdx.x], __ATOMIC_ACQUIRE, __HIP_MEMORY_SCOPE_AGENT);
        for (int o = 32; o; o >>= 1) v += __shfl_down(v, o, 64);
        if (threadIdx.x == 0) out[0] = v * (1.0f / (float)NROWS);
    }
}

extern "C" void kernel_launch(void* const* d_in, const int* in_sizes, int n_in,
                              void* d_out, int out_size, void* d_ws, size_t ws_size,
                              hipStream_t stream) {
    const float* pred      = (const float*)d_in[0];
    const float* seq_pred  = (const float*)d_in[1];
    const int*   label     = (const int*)d_in[2];
    const int*   x_len     = (const int*)d_in[3];
    const int*   label_len = (const int*)d_in[4];
    float* out = (float*)d_out;

    // workspace layout (floats)
    float* w = (float*)d_ws;
    float* lse_pred = w;                       // 16384
    float* sum_pred = w + NROWS;               // 16384
    float* lse_seq  = w + 2 * NROWS;           // 16384
    float* pb       = w + 3 * NROWS;           // 32*512*64 = 1048576
    int*   tg       = (int*)(w + 3 * NROWS + (size_t)BATCH * T_MAX * 64); // 16384 ints
    float* partials = (float*)(tg + NROWS);    // 64
    int*   counter  = (int*)(partials + 64);   // 1

    rowstats_kernel<<<(2 * NROWS) / 4, 256, 0, stream>>>(pred, seq_pred, label,
                                                         lse_pred, sum_pred, lse_seq, pb, counter);
    align_kernel<<<BATCH, 128, 0, stream>>>(pb, x_len, label_len, tg);
    ce_kernel<<<64, 256, 0, stream>>>(pred, label, x_len,
                                      lse_pred, sum_pred, lse_seq, pb, tg,
                                      partials, counter, out);
}

// Round 5
// 222.486 us; speedup vs baseline: 1.0954x; 1.0954x over previous
//
#include <hip/hip_runtime.h>

#define T_MAX 512
#define BATCH 32
#define CLASSES 1296
#define L_MAX 64
#define NROWS (T_MAX * BATCH)   // 16384
#define NV4 (CLASSES / 4)       // 324
#define NINF (-INFINITY)

// DPP wave64 sum: row_shr 1/2/4/8 + row_bcast 15/31. Total lands in LANE 63.
__device__ __forceinline__ float wave_sum64(float v) {
    v += __int_as_float(__builtin_amdgcn_update_dpp(0, __float_as_int(v), 0x111, 0xF, 0xF, true));
    v += __int_as_float(__builtin_amdgcn_update_dpp(0, __float_as_int(v), 0x112, 0xF, 0xF, true));
    v += __int_as_float(__builtin_amdgcn_update_dpp(0, __float_as_int(v), 0x114, 0xF, 0xF, true));
    v += __int_as_float(__builtin_amdgcn_update_dpp(0, __float_as_int(v), 0x118, 0xF, 0xF, true));
    v += __int_as_float(__builtin_amdgcn_update_dpp(0, __float_as_int(v), 0x142, 0xF, 0xF, true));
    v += __int_as_float(__builtin_amdgcn_update_dpp(0, __float_as_int(v), 0x143, 0xF, 0xF, true));
    return v;
}

// ---------------------------------------------------------------------------
// K1 v4: one wave handles BOTH pred row r and seq row r -> 12 float4 loads in
// flight per wave (2x MLP vs v3), half the waves. DPP reductions, no LDS.
// ---------------------------------------------------------------------------
__global__ __launch_bounds__(256) void rowstats_kernel(
    const float* __restrict__ pred, const float* __restrict__ seqp,
    const int* __restrict__ label,
    float* __restrict__ lse_pred, float* __restrict__ sum_pred,
    float* __restrict__ lse_seq, float* __restrict__ pb, int* __restrict__ counter)
{
    int r = blockIdx.x * 4 + (threadIdx.x >> 6);   // row in [0, NROWS)
    int lane = threadIdx.x & 63;
    if (r == 0 && lane == 0) *counter = 0;         // for ce's last-block reduce
    const float* xp = pred + (size_t)r * CLASSES;
    const float* xs = seqp + (size_t)r * CLASSES;
    const float4* p4 = (const float4*)xp;
    const float4* s4 = (const float4*)xs;

    // ---- load phase: 12 vector loads in flight ----
    float4 a0 = p4[lane],       a1 = p4[lane + 64],  a2 = p4[lane + 128];
    float4 a3 = p4[lane + 192], a4 = p4[lane + 256];
    float4 b0 = s4[lane],       b1 = s4[lane + 64],  b2 = s4[lane + 128];
    float4 b3 = s4[lane + 192], b4 = s4[lane + 256];
    float4 at = make_float4(0.f, 0.f, 0.f, 0.f);
    float4 bt = make_float4(0.f, 0.f, 0.f, 0.f);
    if (lane < 4) { at = p4[320 + lane]; bt = s4[320 + lane]; }
    int lab = label[((r & 31) << 6) + lane];

    // ---- compute ----
    float sp = __expf(a0.x) + __expf(a0.y) + __expf(a0.z) + __expf(a0.w)
             + __expf(a1.x) + __expf(a1.y) + __expf(a1.z) + __expf(a1.w)
             + __expf(a2.x) + __expf(a2.y) + __expf(a2.z) + __expf(a2.w)
             + __expf(a3.x) + __expf(a3.y) + __expf(a3.z) + __expf(a3.w)
             + __expf(a4.x) + __expf(a4.y) + __expf(a4.z) + __expf(a4.w);
    float sx = (a0.x + a0.y + a0.z + a0.w) + (a1.x + a1.y + a1.z + a1.w)
             + (a2.x + a2.y + a2.z + a2.w) + (a3.x + a3.y + a3.z + a3.w)
             + (a4.x + a4.y + a4.z + a4.w);
    float ss = __expf(b0.x) + __expf(b0.y) + __expf(b0.z) + __expf(b0.w)
             + __expf(b1.x) + __expf(b1.y) + __expf(b1.z) + __expf(b1.w)
             + __expf(b2.x) + __expf(b2.y) + __expf(b2.z) + __expf(b2.w)
             + __expf(b3.x) + __expf(b3.y) + __expf(b3.z) + __expf(b3.w)
             + __expf(b4.x) + __expf(b4.y) + __expf(b4.z) + __expf(b4.w);
    if (lane < 4) {
        sp += __expf(at.x) + __expf(at.y) + __expf(at.z) + __expf(at.w);
        sx += at.x + at.y + at.z + at.w;
        ss += __expf(bt.x) + __expf(bt.y) + __expf(bt.z) + __expf(bt.w);
    }
    sp = wave_sum64(sp);
    sx = wave_sum64(sx);
    ss = wave_sum64(ss);

    int b = r & 31, t = r >> 5;
    pb[(((size_t)(b << 9) + t) << 6) + lane] = xs[lab];   // seq row is L1-warm
    if (lane == 63) {
        lse_pred[r] = __logf(sp);
        sum_pred[r] = sx;
        lse_seq[r]  = __logf(ss);
    }
}

// ---------------------------------------------------------------------------
// K2 v3: monotonic max-prob alignment, minimal serial chain.
//  - producer wave pre-masks lanes >= R with -inf while staging panels
//  - fast-path body columns: dpp/cndmask/max/add chain + 2-op per-lane choice
//    bit accumulate (no ballot, no band tests)
//  - backtrack: per-ROW jumps via highest-set-bit in cached 32-bit words
//    (<= ~80 LDS-dependent steps instead of 512), then parallel interval fill
// ---------------------------------------------------------------------------
__global__ __launch_bounds__(128) void align_kernel(
    const float* __restrict__ pb, const int* __restrict__ x_len,
    const int* __restrict__ label_len, int* __restrict__ tg)
{
    int b = blockIdx.x;
    int tid = threadIdx.x, w = tid >> 6, lane = tid & 63;
    int C = x_len[b], R = label_len[b];
    int limit = C - R;
    __shared__ float buf[2][4096];       // two 64-col panels (32 KB)
    __shared__ uint2 chw[8 * 64];        // per-panel per-lane choice bits (4 KB)
    __shared__ int a_s[64];              // interval start per row
    __shared__ int rows_s[T_MAX];
    const float* pbb = pb + ((size_t)b << 15);   // b * 512 * 64
    int P = (C + 63) >> 6;

    // producer pre-mask compares (fixed per thread)
    int l0 = (lane & 15) << 2;           // first label-row this float4 covers
    bool mk0 = (l0 + 0) < R, mk1 = (l0 + 1) < R, mk2 = (l0 + 2) < R, mk3 = (l0 + 3) < R;
    bool isb0 = (lane & 15) == 0;
    const int ninf_i = 0xFF800000;

    if (w == 1) {                        // prologue: stage panel 0 (masked)
        const float4* s4 = (const float4*)pbb;
        float4* d4 = (float4*)buf[0];
        #pragma unroll
        for (int k = 0; k < 16; ++k) {
            float4 q = s4[(k << 6) + lane];
            q.x = mk0 ? q.x : NINF;  q.y = mk1 ? q.y : NINF;
            q.z = mk2 ? q.z : NINF;  q.w = mk3 ? q.w : NINF;
            d4[(k << 6) + lane] = q;
        }
    }
    __syncthreads();

    float dp = NINF;
    for (int p = 0; p < P; ++p) {
        if (w == 1) {                    // stage next panel (masked)
            int ldp = p + 1; if (ldp > 7) ldp = 7;
            const float4* s4 = (const float4*)(pbb + (ldp << 12));
            float4* d4 = (float4*)buf[(p + 1) & 1];
            #pragma unroll
            for (int k = 0; k < 16; ++k) {
                float4 q = s4[(k << 6) + lane];
                q.x = mk0 ? q.x : NINF;  q.y = mk1 ? q.y : NINF;
                q.z = mk2 ? q.z : NINF;  q.w = mk3 ? q.w : NINF;
                d4[(k << 6) + lane] = q;
            }
        } else {
            const float* bc = buf[p & 1];
            int base = p << 6;
            unsigned w0 = 0, w1 = 0;
            #pragma unroll
            for (int g = 0; g < 4; ++g) {
                float v[16];
                #pragma unroll
                for (int u = 0; u < 16; ++u) v[u] = bc[((g << 4) + u) * 64 + lane];
                bool general = (p == 0) || (base + (g << 4) + 15 > limit);
                #pragma unroll
                for (int u = 0; u < 16; ++u) {
                    int kk = (g << 4) + u;
                    int j = base + kk;
                    float val;
                    if (general) {
                        if (p == 0 && kk == 0) {            // column 0 init
                            dp = (lane == 0) ? v[0] : NINF;
                            continue;
                        }
                        bool ib = (lane <= j) && (lane >= j - limit);
                        val = ib ? v[u] : NINF;
                    } else {
                        val = v[u];                          // pre-masked
                    }
                    int dpb = __float_as_int(dp);
                    int t1 = __builtin_amdgcn_update_dpp(ninf_i, dpb, 0x111, 0xF, 0xF, false); // row_shr:1
                    int t2 = __builtin_amdgcn_update_dpp(ninf_i, dpb, 0x142, 0xF, 0xF, false); // row_bcast15
                    float shifted = __int_as_float(isb0 ? t2 : t1);
                    bool c = shifted > dp;                   // strict (off critical chain)
                    unsigned bit01 = c ? 1u : 0u;
                    if (kk < 32) w0 |= bit01 << kk; else w1 |= bit01 << (kk - 32);
                    dp = fmaxf(shifted, dp) + val;           // == reference select
                }
            }
            chw[(p << 6) + lane] = make_uint2(w0, w1);
        }
        __syncthreads();
    }

    // backtrack: per-row jumps. bit(row, j) = chw word [(j>>6)][row], half (j>>5)&1
    if (tid == 0) {
        const unsigned* ch32 = (const unsigned*)chw;
        int row = R - 1, j = C - 1;
        while (row > 0 && j >= 0) {
            unsigned word = ch32[((j >> 6) << 7) + (row << 1) + ((j >> 5) & 1)];
            unsigned mb = (2u << (j & 31)) - 1;   // bits 0..(j&31); (j&31)==31 -> 0xFFFFFFFF
            unsigned m = word & mb;
            if (m) {
                int hb = 31 - __clz(m);
                int aj = (j & ~31) | hb;          // column where diagonal fires
                a_s[row] = aj;
                row--; j = aj - 1;
            } else {
                j = (j & ~31) - 1;                // previous 32-col word, same row
            }
        }
        for (int i = row; i >= 0; --i) a_s[i] = 0;
    }
    __syncthreads();
    // parallel interval fill: row i occupies [a_s[i], b_i]
    if (tid < R) {
        int a = a_s[tid];
        int bi = (tid == R - 1) ? (C - 1) : (a_s[tid + 1] - 1);
        for (int j = a; j <= bi; ++j) rows_s[j] = tid;
    }
    __syncthreads();
    for (int j = tid; j < T_MAX; j += 128)
        tg[(b << 9) + j] = (j < C) ? rows_s[j] : -1;
}

// ---------------------------------------------------------------------------
// K3: per-element CE + fused last-block final reduction (agent-scope atomics).
// ---------------------------------------------------------------------------
__global__ __launch_bounds__(256) void ce_kernel(
    const float* __restrict__ pred, const int* __restrict__ label,
    const int* __restrict__ x_len,
    const float* __restrict__ lse_pred, const float* __restrict__ sum_pred,
    const float* __restrict__ lse_seq, const float* __restrict__ pb,
    const int* __restrict__ tg, float* __restrict__ partials,
    int* __restrict__ counter, float* __restrict__ out)
{
    int e = blockIdx.x * 256 + threadIdx.x;    // e = t*BATCH + b
    int t = e >> 5, b = e & 31;
    float ce = 0.f;
    if (t < x_len[b]) {
        int row = tg[(b << 9) + t];
        int tgt = label[(b << 6) + row];
        float lp = lse_pred[e];
        float S = sum_pred[e] - (float)CLASSES * lp;        // sum_v log_softmax(pred)
        float lsp_t = pred[(size_t)e * CLASSES + tgt] - lp;
        float conf = __expf(pb[(((size_t)(b << 9) + t) << 6) + row] - lse_seq[e]);
        float smooth = (1.f - conf) * (1.f / (float)(CLASSES - 1));
        ce = -((conf - smooth) * lsp_t + smooth * S);
    }
    ce = wave_sum64(ce);                        // total in lane 63
    __shared__ float sm[4];
    __shared__ int amLast;
    if ((threadIdx.x & 63) == 63) sm[threadIdx.x >> 6] = ce;
    __syncthreads();
    if (threadIdx.x == 0) {
        float p = sm[0] + sm[1] + sm[2] + sm[3];
        __hip_atomic_store(&partials[blockIdx.x], p, __ATOMIC_RELEASE, __HIP_MEMORY_SCOPE_AGENT);
        amLast = (__hip_atomic_fetch_add(counter, 1, __ATOMIC_ACQ_REL, __HIP_MEMORY_SCOPE_AGENT) == 63);
    }
    __syncthreads();
    if (amLast && threadIdx.x < 64) {
        float v = __hip_atomic_load(&partials[threadIdx.x], __ATOMIC_ACQUIRE, __HIP_MEMORY_SCOPE_AGENT);
        for (int o = 32; o; o >>= 1) v += __shfl_down(v, o, 64);
        if (threadIdx.x == 0) out[0] = v * (1.0f / (float)NROWS);
    }
}

extern "C" void kernel_launch(void* const* d_in, const int* in_sizes, int n_in,
                              void* d_out, int out_size, void* d_ws, size_t ws_size,
                              hipStream_t stream) {
    const float* pred      = (const float*)d_in[0];
    const float* seq_pred  = (const float*)d_in[1];
    const int*   label     = (const int*)d_in[2];
    const int*   x_len     = (const int*)d_in[3];
    const int*   label_len = (const int*)d_in[4];
    float* out = (float*)d_out;

    // workspace layout (floats)
    float* w = (float*)d_ws;
    float* lse_pred = w;                       // 16384
    float* sum_pred = w + NROWS;               // 16384
    float* lse_seq  = w + 2 * NROWS;           // 16384
    float* pb       = w + 3 * NROWS;           // 32*512*64 = 1048576
    int*   tg       = (int*)(w + 3 * NROWS + (size_t)BATCH * T_MAX * 64); // 16384 ints
    float* partials = (float*)(tg + NROWS);    // 64
    int*   counter  = (int*)(partials + 64);   // 1

    rowstats_kernel<<<NROWS / 4, 256, 0, stream>>>(pred, seq_pred, label,
                                                   lse_pred, sum_pred, lse_seq, pb, counter);
    align_kernel<<<BATCH, 128, 0, stream>>>(pb, x_len, label_len, tg);
    ce_kernel<<<64, 256, 0, stream>>>(pred, label, x_len,
                                      lse_pred, sum_pred, lse_seq, pb, tg,
                                      partials, counter, out);
}